// Round 6
// baseline (76.250 us; speedup 1.0000x reference)
//
#include <hip/hip_runtime.h>

#define EPS 1e-5f
#define ONE_M_EPS (1.0f - 1e-5f)
#define NROW 2048
#define FF 20
#define DH 64
#define PADW (DH + 4)        // 68: rows stay 16B-aligned
#define NPAIR (FF * FF)      // 400
#define NPAIR2 (NPAIR + FF)  // + f.Q dots

__device__ __forceinline__ float frcp(float x) { return __builtin_amdgcn_rcpf(x); }
__device__ __forceinline__ float fsq(float x) { return __builtin_amdgcn_sqrtf(x); }

// DPP partial-sum step: x += dpp_shifted(x), masked-off lanes contribute 0
template <int CTRL>
__device__ __forceinline__ float dppadd(float x) {
  int t = __builtin_amdgcn_update_dpp(0, __float_as_int(x), CTRL, 0xf, 0xf, false);
  return x + __int_as_float(t);
}
// full 64-lane sum, broadcast to all lanes via sgpr
__device__ __forceinline__ float wredb(float v) {
  v = dppadd<0x111>(v);  // row_shr:1
  v = dppadd<0x112>(v);  // row_shr:2
  v = dppadd<0x114>(v);  // row_shr:4
  v = dppadd<0x118>(v);  // row_shr:8
  v = dppadd<0x142>(v);  // row_bcast:15
  v = dppadd<0x143>(v);  // row_bcast:31  -> lane63 = total
  return __int_as_float(__builtin_amdgcn_readlane(__float_as_int(v), 63));
}

__device__ __forceinline__ float ftanh(float x) {
  float ax = fabsf(x);
  float e = __expf(-2.f * ax);
  float t = (1.f - e) * frcp(1.f + e);
  return copysignf(t, x);
}

__device__ __forceinline__ float fatanh(float x) {  // x in [0, 1-EPS]
  return 0.5f * __logf((1.f + x) * frcp(1.f - x));
}

__device__ __forceinline__ float clampn(float x) {
  return fminf(fmaxf(x, EPS), ONE_M_EPS);
}

// exp(-acosh(arg)) without exp/log: 1/(arg + sqrt(arg^2-1))
__device__ __forceinline__ float expnacosh(float arg) {
  return frcp(arg + fsq(fmaxf(arg * arg - 1.f, 0.f)));
}

struct FeatParams {
  const float *emb0, *emb1, *win, *bin;
  float* fout;
};

struct ModeParams {
  const float* f;
  const int *Didx, *Qidx;
  const float *q1p, *qp, *qqp, *aw1, *ab1, *aw2, *wout, *bout;
  float* out;
};

// f = exp0(concat(emb0[x0], emb1[x1]) @ win + bin); both modes in one grid
__global__ __launch_bounds__(64) void feat_kernel(const int* __restrict__ x,
                                                  FeatParams ps, FeatParams pc) {
  const int bid = blockIdx.x;
  const int mode = bid >= NROW;
  const FeatParams P = mode ? pc : ps;
  const int n = bid - mode * NROW;
  const int l = threadIdx.x;
  __shared__ float u[DH];
  int x0 = x[n * 2 + 0];
  int x1 = x[n * 2 + 1];
  u[l] = (l < 32) ? P.emb0[x0 * 32 + l] : P.emb1[x1 * 32 + (l - 32)];
  __syncthreads();
  float acc = P.bin[l];
#pragma unroll
  for (int k = 0; k < DH; ++k) acc = fmaf(u[k], P.win[k * DH + l], acc);
  float a2 = wredb(acc * acc);
  float nn = fsq(a2 + 1e-15f);
  P.fout[n * DH + l] = ftanh(nn) * frcp(fmaxf(nn, EPS)) * acc;
}

__global__ __launch_bounds__(256) void mode_kernel(ModeParams pm0, ModeParams pm1) {
  const int bid = blockIdx.x;
  const int mode = bid >= NROW;
  const ModeParams P = mode ? pm1 : pm0;
  const int n = bid - mode * NROW;
  const int tid = threadIdx.x;
  const int l = tid & 63;
  const int w = tid >> 6;

  __shared__ alignas(16) float Ds[FF][PADW];  // D rows; becomes h_neigh after P5
  __shared__ alignas(16) float Qs[FF][PADW];  // raw Q rows (distances)
  __shared__ alignas(16) float fs_[PADW];
  __shared__ alignas(16) float Gm[NPAIR];   // softmax numerators exp(-d)
  __shared__ float Fq[FF];                  // f.Q dots
  __shared__ float D2[FF], DN[FF], DA[FF];  // D2 -> h2 after P5
  __shared__ float Q2[FF], WQ[FF];          // WQ = atanh(|Q|)/|Q|
  __shared__ float zb[2][DH];
  __shared__ float ub[DH];
  __shared__ float pb[4][DH];

  const float* f = P.f;
  float fv = f[n * DH + l];

  // ---- P0: gather tiles ----
  for (int i = w; i < FF; i += 4) {
    Ds[i][l] = f[P.Didx[n * FF + i] * DH + l];
    Qs[i][l] = f[P.Qidx[n * FF + i] * DH + l];
  }
  if (w == 0) fs_[l] = fv;
  float f2 = wredb(fv * fv);
  float fnc = clampn(fsq(f2 + 1e-15f));
  float fA = fatanh(fnc);
  float q1 = P.q1p[0], qsc = P.qp[0], qqsc = P.qqp[0];
  __syncthreads();

  // ---- P1: row norms as per-thread self-dots (wave0: D, wave1: Q) ----
  if (w < 2 && l < FF) {
    const float4* rp =
        (w == 0) ? (const float4*)(&Ds[l][0]) : (const float4*)(&Qs[l][0]);
    float dot = 0.f;
#pragma unroll
    for (int kk = 0; kk < DH / 4; ++kk) {
      float4 a = rp[kk];
      dot = fmaf(a.x, a.x, dot);
      dot = fmaf(a.y, a.y, dot);
      dot = fmaf(a.z, a.z, dot);
      dot = fmaf(a.w, a.w, dot);
    }
    float nc = clampn(fsq(dot + 1e-15f));
    float at = fatanh(nc);
    if (w == 0) {
      D2[l] = dot; DN[l] = nc; DA[l] = at;
    } else {
      Q2[l] = dot; WQ[l] = at * frcp(nc);
    }
  }
  __syncthreads();

  // scaled Q columns in registers: qregS[j] = (atanh(|Q_j|)/|Q_j|) * Q_j[l]
  float qregS[FF];
#pragma unroll
  for (int j = 0; j < FF; ++j) qregS[j] = WQ[j] * Qs[j][l];

  // ---- P2: pair dots, 2 per thread interleaved -> softmax numerators ----
  {
    const int p0 = tid;
    const int p1 = tid + 256;
    const bool v1 = (p1 < NPAIR2);
    const int p1c = v1 ? p1 : 0;
    const int i0 = p0 / FF, j0 = p0 - i0 * FF;
    const int i1 = p1c / FF, j1 = p1c - i1 * FF;
    const float4* a0 =
        (i0 < FF) ? (const float4*)(&Ds[i0][0]) : (const float4*)(&fs_[0]);
    const float4* b0 = (const float4*)(&Qs[j0][0]);
    const float4* a1 =
        (i1 < FF) ? (const float4*)(&Ds[i1][0]) : (const float4*)(&fs_[0]);
    const float4* b1 = (const float4*)(&Qs[j1][0]);
    float d0 = 0.f, d1 = 0.f;
#pragma unroll
    for (int kk = 0; kk < DH / 4; ++kk) {
      float4 xa = a0[kk], xb = b0[kk], ya = a1[kk], yb = b1[kk];
      d0 = fmaf(xa.x, xb.x, d0);
      d0 = fmaf(xa.y, xb.y, d0);
      d0 = fmaf(xa.z, xb.z, d0);
      d0 = fmaf(xa.w, xb.w, d0);
      d1 = fmaf(ya.x, yb.x, d1);
      d1 = fmaf(ya.y, yb.y, d1);
      d1 = fmaf(ya.z, yb.z, d1);
      d1 = fmaf(ya.w, yb.w, d1);
    }
    auto emit = [&](int i, int j, int p, float dot) {
      if (i < FF) {
        float d2 = D2[i] + Q2[j] - 2.f * dot;
        float den = fmaxf((1.f - D2[i]) * (1.f - Q2[j]), EPS);
        float arg = fmaxf(1.f + 2.f * d2 * frcp(den), 1.f + 1e-7f);
        Gm[p] = expnacosh(arg);
      } else {
        Fq[j] = dot;
      }
    };
    emit(i0, j0, p0, d0);
    if (v1) emit(i1, j1, p1c, d1);
  }
  __syncthreads();

  // ---- P5: per-slot weighted sums; batched DPP reductions for ILP ----
  {
    float acc_[5], dl_[5];
#pragma unroll
    for (int s5 = 0; s5 < 5; ++s5) {
      const int i = w + 4 * s5;
      const float4* gr = (const float4*)(&Gm[i * FF]);
      float ssum = 0.f, accR = 0.f;
#pragma unroll
      for (int jq = 0; jq < FF / 4; ++jq) {
        float4 g4 = gr[jq];
        ssum += ((g4.x + g4.y) + (g4.z + g4.w));
        accR = fmaf(g4.x, qregS[4 * jq + 0], accR);
        accR = fmaf(g4.y, qregS[4 * jq + 1], accR);
        accR = fmaf(g4.z, qregS[4 * jq + 2], accR);
        accR = fmaf(g4.w, qregS[4 * jq + 3], accR);
      }
      acc_[s5] = accR * frcp(ssum);
      dl_[s5] = Ds[i][l];
    }
    float a2_[5], xy_[5];
#pragma unroll
    for (int s5 = 0; s5 < 5; ++s5) {
      a2_[s5] = wredb(acc_[s5] * acc_[s5]);
      xy_[s5] = wredb(dl_[s5] * acc_[s5]);
    }
#pragma unroll
    for (int s5 = 0; s5 < 5; ++s5) {
      const int i = w + 4 * s5;
      float a2 = a2_[s5];
      float nn = fsq(a2 + 1e-15f);
      float ec = ftanh(nn) * frcp(fmaxf(nn, EPS));
      float fDc = ftanh(q1 * DA[i]) * frcp(DN[i]);
      float x2 = fDc * fDc * D2[i];
      float y2 = ec * ec * a2;
      float xy = fDc * ec * xy_[s5];
      float al = 1.f + 2.f * xy + y2;
      float be = 1.f - x2;
      float rd = frcp(fmaxf(1.f + 2.f * xy + x2 * y2, EPS));
      Ds[i][l] = (al * fDc * dl_[s5] + be * ec * acc_[s5]) * rd;
      float h2 = (al * al * x2 + 2.f * al * be * xy + be * be * y2) * rd * rd;
      if (l == 0) D2[i] = h2;  // norm chain deferred to P6
    }
  }
  __syncthreads();

  // ---- P6: aggregates (wave0: e1 over H; wave1: e2 over Q) ----
  if (w < 2) {
    float a1 = 0.f;
    float wh = 1.f;
    if (w == 0) {
      if (l < FF) {
        float h2 = D2[l];
        float nc = clampn(fsq(h2 + 1e-15f));
        wh = fatanh(nc) * frcp(nc);  // log0 weight for H rows
        const float4* ap = (const float4*)(&fs_[0]);
        const float4* bp = (const float4*)(&Ds[l][0]);
        float dot = 0.f;
#pragma unroll
        for (int kk = 0; kk < DH / 4; ++kk) {
          float4 a = ap[kk];
          float4 b = bp[kk];
          dot = fmaf(a.x, b.x, dot);
          dot = fmaf(a.y, b.y, dot);
          dot = fmaf(a.z, b.z, dot);
          dot = fmaf(a.w, b.w, dot);
        }
        float d2 = f2 + h2 - 2.f * dot;
        float den = fmaxf((1.f - f2) * (1.f - h2), EPS);
        float arg = fmaxf(1.f + 2.f * d2 * frcp(den), 1.f + 1e-7f);
        a1 = expnacosh(arg);
      }
    } else {
      if (l < FF) {
        float d2 = f2 + Q2[l] - 2.f * Fq[l];
        float den = fmaxf((1.f - f2) * (1.f - Q2[l]), EPS);
        float arg = fmaxf(1.f + 2.f * d2 * frcp(den), 1.f + 1e-7f);
        a1 = expnacosh(arg);
      }
    }
    float s = wredb(a1);
    float c = (l < FF) ? a1 * frcp(s) * wh : 0.f;  // wave1: wh=1 (folded in qregS)
    float accE = 0.f;
    if (w == 0) {
#pragma unroll
      for (int j = 0; j < FF; ++j) {
        float cj = __int_as_float(__builtin_amdgcn_readlane(__float_as_int(c), j));
        accE = fmaf(cj, Ds[j][l], accE);
      }
    } else {
#pragma unroll
      for (int j = 0; j < FF; ++j) {
        float cj = __int_as_float(__builtin_amdgcn_readlane(__float_as_int(c), j));
        accE = fmaf(cj, qregS[j], accE);
      }
    }
    float a2 = wredb(accE * accE);
    float nn = fsq(a2 + 1e-15f);
    float ec = ftanh(nn) * frcp(fmaxf(nn, EPS));
    float nTE = ec * accE;
    float r = (w == 0) ? qsc : qqsc;
    float fsc = ftanh(r * fA) * frcp(fnc);
    float xv = fsc * fv;
    float x2 = fsc * fsc * f2;
    float y2 = ec * ec * a2;
    float xy = wredb(xv * nTE);
    float al = 1.f + 2.f * xy + y2;
    float be = 1.f - x2;
    float rd = frcp(fmaxf(1.f + 2.f * xy + x2 * y2, EPS));
    float ev = (al * xv + be * nTE) * rd;
    float es = (al * al * x2 + 2.f * al * be * xy + be * be * y2) * rd * rd;
    float n1 = clampn(fsq(es + 1e-15f));
    zb[w][l] = fatanh(n1) * frcp(n1) * ev;
  }
  __syncthreads();

  // ---- P7: beta softmax + rst + u (wave0) ----
  if (w == 0) {
    int p_ = l >> 5, c_ = l & 31;
    float mm = P.ab1[c_];
#pragma unroll
    for (int k = 0; k < DH; ++k) mm = fmaf(zb[p_][k], P.aw1[k * 32 + c_], mm);
    float tt = ftanh(mm);
    float sr = tt * P.aw2[c_];
    sr = dppadd<0x111>(sr);
    sr = dppadd<0x112>(sr);
    sr = dppadd<0x114>(sr);
    sr = dppadd<0x118>(sr);
    sr = dppadd<0x142>(sr);  // lane31 = sum(0..31), lane63 = sum(32..63)
    float s0 = __int_as_float(__builtin_amdgcn_readlane(__float_as_int(sr), 31));
    float s1 = __int_as_float(__builtin_amdgcn_readlane(__float_as_int(sr), 63));
    float bm = fmaxf(s0, s1);
    float b0 = __expf(s0 - bm), b1 = __expf(s1 - bm);
    float bi = frcp(b0 + b1);
    b0 *= bi;
    b1 *= bi;
    float rv = fmaf(b0, zb[0][l], b1 * zb[1][l]);
    float r2 = wredb(rv * rv);
    float rn = fsq(r2 + 1e-15f);
    float sc = ftanh(rn) * frcp(fmaxf(rn, EPS));
    float rst = sc * rv;
    float rr = sc * sc * r2;
    float rc = clampn(fsq(rr + 1e-15f));
    ub[l] = fatanh(rc) * frcp(rc) * rst;
  }
  __syncthreads();

  // ---- P8: out = exp0(u @ wout + bout), k-split over 4 waves ----
  {
    float oo = 0.f;
#pragma unroll
    for (int k = 0; k < DH / 4; ++k) {
      int kk = w * (DH / 4) + k;
      oo = fmaf(ub[kk], P.wout[kk * DH + l], oo);
    }
    pb[w][l] = oo;
  }
  __syncthreads();
  if (w == 0) {
    float oo = P.bout[l] + ((pb[0][l] + pb[1][l]) + (pb[2][l] + pb[3][l]));
    float o2 = wredb(oo * oo);
    float on = fsq(o2 + 1e-15f);
    P.out[n * DH + l] = ftanh(on) * frcp(fmaxf(on, EPS)) * oo;
  }
}

extern "C" void kernel_launch(void* const* d_in, const int* in_sizes, int n_in,
                              void* d_out, int out_size, void* d_ws,
                              size_t ws_size, hipStream_t stream) {
  const int* x = (const int*)d_in[0];
  const int* idx_sim = (const int*)d_in[1];
  const int* idx_cor = (const int*)d_in[2];
  const float* p[2][12];
  for (int m = 0; m < 2; ++m)
    for (int k = 0; k < 12; ++k) p[m][k] = (const float*)d_in[3 + m * 12 + k];

  float* fsim = (float*)d_ws;
  float* fcor = fsim + NROW * DH;
  float* out = (float*)d_out;

  FeatParams fps = {p[0][0], p[0][1], p[0][2], p[0][3], fsim};
  FeatParams fpc = {p[1][0], p[1][1], p[1][2], p[1][3], fcor};
  feat_kernel<<<2 * NROW, 64, 0, stream>>>(x, fps, fpc);

  // mode 'sim': D = f[idx_cor], Q = f[idx_sim]; mode 'cor': swapped
  ModeParams m0 = {fsim, idx_cor, idx_sim, p[0][6], p[0][4], p[0][5],
                   p[0][7], p[0][8], p[0][9], p[0][10], p[0][11], out};
  ModeParams m1 = {fcor, idx_sim, idx_cor, p[1][6], p[1][4], p[1][5],
                   p[1][7], p[1][8], p[1][9], p[1][10], p[1][11], out + NROW * DH};
  mode_kernel<<<2 * NROW, 256, 0, stream>>>(m0, m1);
}

// Round 7
// 45.475 us; speedup vs baseline: 1.6768x; 1.6768x over previous
//
#include <hip/hip_runtime.h>

#define EPS 1e-5f
#define ONE_M_EPS (1.0f - 1e-5f)
#define NROW 2048
#define FF 20
#define DH 64
#define PADW (DH + 4)        // 68: rows stay 16B-aligned
#define NPAIR (FF * FF)      // 400
#define NPAIR2 (NPAIR + FF)  // + f.Q dots

__device__ __forceinline__ float frcp(float x) { return __builtin_amdgcn_rcpf(x); }
__device__ __forceinline__ float fsq(float x) { return __builtin_amdgcn_sqrtf(x); }

// DPP partial-sum step
template <int CTRL>
__device__ __forceinline__ float dppadd(float x) {
  int t = __builtin_amdgcn_update_dpp(0, __float_as_int(x), CTRL, 0xf, 0xf, false);
  return x + __int_as_float(t);
}
// full 64-lane sum, broadcast via readlane(63)
__device__ __forceinline__ float wredb(float v) {
  v = dppadd<0x111>(v);  // row_shr:1
  v = dppadd<0x112>(v);  // row_shr:2
  v = dppadd<0x114>(v);  // row_shr:4
  v = dppadd<0x118>(v);  // row_shr:8
  v = dppadd<0x142>(v);  // row_bcast:15
  v = dppadd<0x143>(v);  // row_bcast:31 -> lane63 = total
  return __int_as_float(__builtin_amdgcn_readlane(__float_as_int(v), 63));
}

__device__ __forceinline__ float ftanh(float x) {
  float ax = fabsf(x);
  float e = __expf(-2.f * ax);
  float t = (1.f - e) * frcp(1.f + e);
  return copysignf(t, x);
}

__device__ __forceinline__ float fatanh(float x) {  // x in [0, 1-EPS]
  return 0.5f * __logf((1.f + x) * frcp(1.f - x));
}

__device__ __forceinline__ float clampn(float x) {
  return fminf(fmaxf(x, EPS), ONE_M_EPS);
}

// exp(-acosh(arg)) = 1/(arg + sqrt(arg^2-1)), exact
__device__ __forceinline__ float expnacosh(float arg) {
  return frcp(arg + fsq(fmaxf(arg * arg - 1.f, 0.f)));
}

struct FeatParams {
  const float *emb0, *emb1, *win, *bin;
  float* fout;
};

struct ModeParams {
  const float* f;
  const int *Didx, *Qidx;
  const float *q1p, *qp, *qqp, *aw1, *ab1, *aw2, *wout, *bout;
  float* out;
};

__global__ __launch_bounds__(64) void feat_kernel(const int* __restrict__ x,
                                                  FeatParams ps, FeatParams pc) {
  const int bid = blockIdx.x;
  const int mode = bid >= NROW;
  const FeatParams P = mode ? pc : ps;
  const int n = bid - mode * NROW;
  const int l = threadIdx.x;
  __shared__ float u[DH];
  int x0 = x[n * 2 + 0];
  int x1 = x[n * 2 + 1];
  u[l] = (l < 32) ? P.emb0[x0 * 32 + l] : P.emb1[x1 * 32 + (l - 32)];
  __syncthreads();
  float acc = P.bin[l];
#pragma unroll
  for (int k = 0; k < DH; ++k) acc = fmaf(u[k], P.win[k * DH + l], acc);
  float a2 = wredb(acc * acc);
  float nn = fsq(a2 + 1e-15f);
  P.fout[n * DH + l] = ftanh(nn) * frcp(fmaxf(nn, EPS)) * acc;
}

__global__ __launch_bounds__(256) void mode_kernel(ModeParams pm0, ModeParams pm1) {
  const int bid = blockIdx.x;
  const int mode = bid >= NROW;
  const ModeParams P = mode ? pm1 : pm0;
  const int n = bid - mode * NROW;
  const int tid = threadIdx.x;
  const int l = tid & 63;
  const int w = tid >> 6;

  __shared__ alignas(16) float Ds[FF][PADW];  // D rows -> h rows after P5
  __shared__ alignas(16) float Qs[FF][PADW];  // raw Q -> scaled Q after P2
  __shared__ alignas(16) float fs_[PADW];
  __shared__ alignas(16) float Gm[NPAIR];   // softmax numerators exp(-d)
  __shared__ float Fq[FF];                  // f.Q raw dots
  __shared__ float D2[FF], DN[FF], DA[FF];  // D2 -> h2 after P5
  __shared__ float Q2[FF], WQ[FF];          // WQ = atanh(|Q|)/|Q|
  __shared__ float zb[2][DH];
  __shared__ float ub[DH];
  __shared__ float pb[4][DH];

  const float* f = P.f;
  float fv = f[n * DH + l];

  // ---- P0: gather tiles ----
  for (int i = w; i < FF; i += 4) {
    Ds[i][l] = f[P.Didx[n * FF + i] * DH + l];
    Qs[i][l] = f[P.Qidx[n * FF + i] * DH + l];
  }
  if (w == 0) fs_[l] = fv;
  float f2 = wredb(fv * fv);
  float fnc = clampn(fsq(f2 + 1e-15f));
  float fA = fatanh(fnc);
  float q1 = P.q1p[0], qsc = P.qp[0], qqsc = P.qqp[0];
  __syncthreads();

  // ---- P1: row norms as per-thread self-dots (wave0: D, wave1: Q) ----
  if (w < 2 && l < FF) {
    const float4* rp =
        (w == 0) ? (const float4*)(&Ds[l][0]) : (const float4*)(&Qs[l][0]);
    float dot = 0.f;
#pragma unroll
    for (int kk = 0; kk < DH / 4; ++kk) {
      float4 a = rp[kk];
      dot = fmaf(a.x, a.x, dot);
      dot = fmaf(a.y, a.y, dot);
      dot = fmaf(a.z, a.z, dot);
      dot = fmaf(a.w, a.w, dot);
    }
    float nc = clampn(fsq(dot + 1e-15f));
    float at = fatanh(nc);
    if (w == 0) {
      D2[l] = dot; DN[l] = nc; DA[l] = at;
    } else {
      Q2[l] = dot; WQ[l] = at * frcp(nc);
    }
  }
  __syncthreads();

  // ---- P2: pair dots (raw Q) -> softmax numerators ----
  for (int p = tid; p < NPAIR2; p += 256) {
    int i = p / FF;
    int j = p - i * FF;
    const float4* ap =
        (i < FF) ? (const float4*)(&Ds[i][0]) : (const float4*)(&fs_[0]);
    const float4* bp = (const float4*)(&Qs[j][0]);
    float dot = 0.f;
#pragma unroll
    for (int kk = 0; kk < DH / 4; ++kk) {
      float4 a = ap[kk];
      float4 b = bp[kk];
      dot = fmaf(a.x, b.x, dot);
      dot = fmaf(a.y, b.y, dot);
      dot = fmaf(a.z, b.z, dot);
      dot = fmaf(a.w, b.w, dot);
    }
    if (i < FF) {
      float d2 = D2[i] + Q2[j] - 2.f * dot;
      float den = fmaxf((1.f - D2[i]) * (1.f - Q2[j]), EPS);
      float arg = fmaxf(1.f + 2.f * d2 * frcp(den), 1.f + 1e-7f);
      Gm[p] = expnacosh(arg);
    } else {
      Fq[j] = dot;
    }
  }
  __syncthreads();

  // ---- P3: scale Q rows in place: Qs[i] *= atanh(|Q_i|)/|Q_i| ----
  for (int i = w; i < FF; i += 4) Qs[i][l] *= WQ[i];
  __syncthreads();

  // ---- P5: per-slot weighted sum (softmax + log0/mob_scalar collapsed) ----
#pragma unroll 1
  for (int i = w; i < FF; i += 4) {
    const float4* gr = (const float4*)(&Gm[i * FF]);
    float ssum = 0.f, accR = 0.f;
#pragma unroll
    for (int jq = 0; jq < FF / 4; ++jq) {
      float4 g4 = gr[jq];
      ssum += ((g4.x + g4.y) + (g4.z + g4.w));
      accR = fmaf(g4.x, Qs[4 * jq + 0][l], accR);
      accR = fmaf(g4.y, Qs[4 * jq + 1][l], accR);
      accR = fmaf(g4.z, Qs[4 * jq + 2][l], accR);
      accR = fmaf(g4.w, Qs[4 * jq + 3][l], accR);
    }
    float acc = accR * frcp(ssum);
    float dl = Ds[i][l];
    float a2 = wredb(acc * acc);
    float xy0 = wredb(dl * acc);
    float nn = fsq(a2 + 1e-15f);
    float ec = ftanh(nn) * frcp(fmaxf(nn, EPS));
    float fDc = ftanh(q1 * DA[i]) * frcp(DN[i]);
    float x2 = fDc * fDc * D2[i];
    float y2 = ec * ec * a2;
    float xy = fDc * ec * xy0;
    float al = 1.f + 2.f * xy + y2;
    float be = 1.f - x2;
    float rd = frcp(fmaxf(1.f + 2.f * xy + x2 * y2, EPS));
    Ds[i][l] = (al * fDc * dl + be * ec * acc) * rd;
    float h2 = (al * al * x2 + 2.f * al * be * xy + be * be * y2) * rd * rd;
    if (l == 0) D2[i] = h2;  // norm chain deferred to P6
  }
  __syncthreads();

  // ---- P6: aggregates (wave0: e1 over H; wave1: e2 over scaled Q) ----
  if (w < 2) {
    float a1 = 0.f;
    float wh = 1.f;
    if (w == 0) {
      if (l < FF) {
        float h2 = D2[l];
        float nc = clampn(fsq(h2 + 1e-15f));
        wh = fatanh(nc) * frcp(nc);  // log0 weight for H rows
        const float4* ap = (const float4*)(&fs_[0]);
        const float4* bp = (const float4*)(&Ds[l][0]);
        float dot = 0.f;
#pragma unroll
        for (int kk = 0; kk < DH / 4; ++kk) {
          float4 a = ap[kk];
          float4 b = bp[kk];
          dot = fmaf(a.x, b.x, dot);
          dot = fmaf(a.y, b.y, dot);
          dot = fmaf(a.z, b.z, dot);
          dot = fmaf(a.w, b.w, dot);
        }
        float d2 = f2 + h2 - 2.f * dot;
        float den = fmaxf((1.f - f2) * (1.f - h2), EPS);
        float arg = fmaxf(1.f + 2.f * d2 * frcp(den), 1.f + 1e-7f);
        a1 = expnacosh(arg);
      }
    } else {
      if (l < FF) {
        float d2 = f2 + Q2[l] - 2.f * Fq[l];
        float den = fmaxf((1.f - f2) * (1.f - Q2[l]), EPS);
        float arg = fmaxf(1.f + 2.f * d2 * frcp(den), 1.f + 1e-7f);
        a1 = expnacosh(arg);
      }
    }
    float s = wredb(a1);
    float c = (l < FF) ? a1 * frcp(s) * wh : 0.f;  // wave1: weight in scaled Q
    float accE = 0.f;
    if (w == 0) {
#pragma unroll
      for (int j = 0; j < FF; ++j) {
        float cj = __int_as_float(__builtin_amdgcn_readlane(__float_as_int(c), j));
        accE = fmaf(cj, Ds[j][l], accE);
      }
    } else {
#pragma unroll
      for (int j = 0; j < FF; ++j) {
        float cj = __int_as_float(__builtin_amdgcn_readlane(__float_as_int(c), j));
        accE = fmaf(cj, Qs[j][l], accE);
      }
    }
    float a2 = wredb(accE * accE);
    float nn = fsq(a2 + 1e-15f);
    float ec = ftanh(nn) * frcp(fmaxf(nn, EPS));
    float nTE = ec * accE;
    float r = (w == 0) ? qsc : qqsc;
    float fsc = ftanh(r * fA) * frcp(fnc);
    float xv = fsc * fv;
    float x2 = fsc * fsc * f2;
    float y2 = ec * ec * a2;
    float xy = wredb(xv * nTE);
    float al = 1.f + 2.f * xy + y2;
    float be = 1.f - x2;
    float rd = frcp(fmaxf(1.f + 2.f * xy + x2 * y2, EPS));
    float ev = (al * xv + be * nTE) * rd;
    float es = (al * al * x2 + 2.f * al * be * xy + be * be * y2) * rd * rd;
    float n1 = clampn(fsq(es + 1e-15f));
    zb[w][l] = fatanh(n1) * frcp(n1) * ev;
  }
  __syncthreads();

  // ---- P7: beta softmax + rst + u (wave0) ----
  if (w == 0) {
    int p_ = l >> 5, c_ = l & 31;
    float mm = P.ab1[c_];
#pragma unroll
    for (int k = 0; k < DH; ++k) mm = fmaf(zb[p_][k], P.aw1[k * 32 + c_], mm);
    float tt = ftanh(mm);
    float sr = tt * P.aw2[c_];
    sr = dppadd<0x111>(sr);
    sr = dppadd<0x112>(sr);
    sr = dppadd<0x114>(sr);
    sr = dppadd<0x118>(sr);
    sr = dppadd<0x142>(sr);  // lane31 = sum(0..31), lane63 = sum(32..63)
    float s0 = __int_as_float(__builtin_amdgcn_readlane(__float_as_int(sr), 31));
    float s1 = __int_as_float(__builtin_amdgcn_readlane(__float_as_int(sr), 63));
    float bm = fmaxf(s0, s1);
    float b0 = __expf(s0 - bm), b1 = __expf(s1 - bm);
    float bi = frcp(b0 + b1);
    b0 *= bi;
    b1 *= bi;
    float rv = fmaf(b0, zb[0][l], b1 * zb[1][l]);
    float r2 = wredb(rv * rv);
    float rn = fsq(r2 + 1e-15f);
    float sc = ftanh(rn) * frcp(fmaxf(rn, EPS));
    float rst = sc * rv;
    float rr = sc * sc * r2;
    float rc = clampn(fsq(rr + 1e-15f));
    ub[l] = fatanh(rc) * frcp(rc) * rst;
  }
  __syncthreads();

  // ---- P8: out = exp0(u @ wout + bout), k-split over 4 waves ----
  {
    float oo = 0.f;
#pragma unroll
    for (int k = 0; k < DH / 4; ++k) {
      int kk = w * (DH / 4) + k;
      oo = fmaf(ub[kk], P.wout[kk * DH + l], oo);
    }
    pb[w][l] = oo;
  }
  __syncthreads();
  if (w == 0) {
    float oo = P.bout[l] + ((pb[0][l] + pb[1][l]) + (pb[2][l] + pb[3][l]));
    float o2 = wredb(oo * oo);
    float on = fsq(o2 + 1e-15f);
    P.out[n * DH + l] = ftanh(on) * frcp(fmaxf(on, EPS)) * oo;
  }
}

extern "C" void kernel_launch(void* const* d_in, const int* in_sizes, int n_in,
                              void* d_out, int out_size, void* d_ws,
                              size_t ws_size, hipStream_t stream) {
  const int* x = (const int*)d_in[0];
  const int* idx_sim = (const int*)d_in[1];
  const int* idx_cor = (const int*)d_in[2];
  const float* p[2][12];
  for (int m = 0; m < 2; ++m)
    for (int k = 0; k < 12; ++k) p[m][k] = (const float*)d_in[3 + m * 12 + k];

  float* fsim = (float*)d_ws;
  float* fcor = fsim + NROW * DH;
  float* out = (float*)d_out;

  FeatParams fps = {p[0][0], p[0][1], p[0][2], p[0][3], fsim};
  FeatParams fpc = {p[1][0], p[1][1], p[1][2], p[1][3], fcor};
  feat_kernel<<<2 * NROW, 64, 0, stream>>>(x, fps, fpc);

  // mode 'sim': D = f[idx_cor], Q = f[idx_sim]; mode 'cor': swapped
  ModeParams m0 = {fsim, idx_cor, idx_sim, p[0][6], p[0][4], p[0][5],
                   p[0][7], p[0][8], p[0][9], p[0][10], p[0][11], out};
  ModeParams m1 = {fcor, idx_sim, idx_cor, p[1][6], p[1][4], p[1][5],
                   p[1][7], p[1][8], p[1][9], p[1][10], p[1][11], out + NROW * DH};
  mode_kernel<<<2 * NROW, 256, 0, stream>>>(m0, m1);
}

// Round 8
// 44.754 us; speedup vs baseline: 1.7037x; 1.0161x over previous
//
#include <hip/hip_runtime.h>

#define EPS 1e-5f
#define ONE_M_EPS (1.0f - 1e-5f)
#define NROW 2048
#define FF 20
#define DH 64
#define PADW (DH + 4)        // 68: rows stay 16B-aligned
#define NPAIR (FF * FF)      // 400
#define NPAIR2 (NPAIR + FF)  // + f.Q dots

typedef float v2f __attribute__((ext_vector_type(2)));

__device__ __forceinline__ float frcp(float x) { return __builtin_amdgcn_rcpf(x); }
__device__ __forceinline__ float fsq(float x) { return __builtin_amdgcn_sqrtf(x); }
__device__ __forceinline__ v2f pkfma(v2f a, v2f b, v2f c) {
  return __builtin_elementwise_fma(a, b, c);
}

// DPP partial-sum step
template <int CTRL>
__device__ __forceinline__ float dppadd(float x) {
  int t = __builtin_amdgcn_update_dpp(0, __float_as_int(x), CTRL, 0xf, 0xf, false);
  return x + __int_as_float(t);
}
// full 64-lane sum, broadcast via readlane(63)
__device__ __forceinline__ float wredb(float v) {
  v = dppadd<0x111>(v);  // row_shr:1
  v = dppadd<0x112>(v);  // row_shr:2
  v = dppadd<0x114>(v);  // row_shr:4
  v = dppadd<0x118>(v);  // row_shr:8
  v = dppadd<0x142>(v);  // row_bcast:15
  v = dppadd<0x143>(v);  // row_bcast:31 -> lane63 = total
  return __int_as_float(__builtin_amdgcn_readlane(__float_as_int(v), 63));
}

__device__ __forceinline__ float ftanh(float x) {
  float ax = fabsf(x);
  float e = __expf(-2.f * ax);
  float t = (1.f - e) * frcp(1.f + e);
  return copysignf(t, x);
}

__device__ __forceinline__ float fatanh(float x) {  // x in [0, 1-EPS]
  return 0.5f * __logf((1.f + x) * frcp(1.f - x));
}

__device__ __forceinline__ float clampn(float x) {
  return fminf(fmaxf(x, EPS), ONE_M_EPS);
}

// exp(-acosh(arg)) = 1/(arg + sqrt(arg^2-1)), exact
__device__ __forceinline__ float expnacosh(float arg) {
  return frcp(arg + fsq(fmaxf(arg * arg - 1.f, 0.f)));
}

// packed 64-elem dot of two 16B-aligned rows
__device__ __forceinline__ float dot64(const float* __restrict__ a,
                                       const float* __restrict__ b) {
  const float4* ap = (const float4*)a;
  const float4* bp = (const float4*)b;
  v2f acc = {0.f, 0.f};
#pragma unroll
  for (int kk = 0; kk < DH / 4; ++kk) {
    float4 x = ap[kk];
    float4 y = bp[kk];
    acc = pkfma(v2f{x.x, x.y}, v2f{y.x, y.y}, acc);
    acc = pkfma(v2f{x.z, x.w}, v2f{y.z, y.w}, acc);
  }
  return acc.x + acc.y;
}

struct FeatParams {
  const float *emb0, *emb1, *win, *bin;
  float* fout;
};

struct ModeParams {
  const float* f;
  const int *Didx, *Qidx;
  const float *q1p, *qp, *qqp, *aw1, *ab1, *aw2, *wout, *bout;
  float* out;
};

__global__ __launch_bounds__(64) void feat_kernel(const int* __restrict__ x,
                                                  FeatParams ps, FeatParams pc) {
  const int bid = blockIdx.x;
  const int mode = bid >= NROW;
  const FeatParams P = mode ? pc : ps;
  const int n = bid - mode * NROW;
  const int l = threadIdx.x;
  __shared__ float u[DH];
  int x0 = x[n * 2 + 0];
  int x1 = x[n * 2 + 1];
  u[l] = (l < 32) ? P.emb0[x0 * 32 + l] : P.emb1[x1 * 32 + (l - 32)];
  __syncthreads();
  v2f acc2 = {P.bin[l], 0.f};
#pragma unroll
  for (int k = 0; k < DH; k += 2) {
    v2f uv = *(const v2f*)&u[k];
    v2f wv = {P.win[k * DH + l], P.win[(k + 1) * DH + l]};
    acc2 = pkfma(uv, wv, acc2);
  }
  float acc = acc2.x + acc2.y;
  float a2 = wredb(acc * acc);
  float nn = fsq(a2 + 1e-15f);
  P.fout[n * DH + l] = ftanh(nn) * frcp(fmaxf(nn, EPS)) * acc;
}

__global__ __launch_bounds__(256) void mode_kernel(ModeParams pm0, ModeParams pm1) {
  const int bid = blockIdx.x;
  const int mode = bid >= NROW;
  const ModeParams P = mode ? pm1 : pm0;
  const int n = bid - mode * NROW;
  const int tid = threadIdx.x;
  const int l = tid & 63;
  const int w = tid >> 6;

  __shared__ alignas(16) float Ds[FF][PADW];  // D rows -> h rows after P5
  __shared__ alignas(16) float Qs[FF][PADW];  // raw Q -> scaled Q after P3
  __shared__ alignas(16) float fs_[PADW];
  __shared__ alignas(16) float Gm[NPAIR];   // softmax numerators exp(-d)
  __shared__ float Fq[FF];                  // f.Q raw dots
  __shared__ float D2[FF], DN[FF], DA[FF];  // D2 -> h2 after P5
  __shared__ float Q2[FF], WQ[FF];          // WQ = atanh(|Q|)/|Q|
  __shared__ float zb[2][DH];
  __shared__ float ub[DH];
  __shared__ float pb[4][DH];

  const float* f = P.f;
  float fv = f[n * DH + l];

  // ---- P0: gather tiles ----
  for (int i = w; i < FF; i += 4) {
    Ds[i][l] = f[P.Didx[n * FF + i] * DH + l];
    Qs[i][l] = f[P.Qidx[n * FF + i] * DH + l];
  }
  if (w == 0) fs_[l] = fv;
  float f2 = wredb(fv * fv);
  float fnc = clampn(fsq(f2 + 1e-15f));
  float fA = fatanh(fnc);
  float q1 = P.q1p[0], qsc = P.qp[0], qqsc = P.qqp[0];
  __syncthreads();

  // ---- P1: row norms as per-thread self-dots (wave0: D, wave1: Q) ----
  if (w < 2 && l < FF) {
    const float* rp = (w == 0) ? &Ds[l][0] : &Qs[l][0];
    float dot = dot64(rp, rp);
    float nc = clampn(fsq(dot + 1e-15f));
    float at = fatanh(nc);
    if (w == 0) {
      D2[l] = dot; DN[l] = nc; DA[l] = at;
    } else {
      Q2[l] = dot; WQ[l] = at * frcp(nc);
    }
  }
  __syncthreads();

  // ---- P2: pair dots (raw Q) -> softmax numerators ----
  for (int p = tid; p < NPAIR2; p += 256) {
    int i = p / FF;
    int j = p - i * FF;
    const float* ap = (i < FF) ? &Ds[i][0] : &fs_[0];
    float dot = dot64(ap, &Qs[j][0]);
    if (i < FF) {
      float d2 = D2[i] + Q2[j] - 2.f * dot;
      float den = fmaxf((1.f - D2[i]) * (1.f - Q2[j]), EPS);
      float arg = fmaxf(1.f + 2.f * d2 * frcp(den), 1.f + 1e-7f);
      Gm[p] = expnacosh(arg);
    } else {
      Fq[j] = dot;
    }
  }
  __syncthreads();

  // ---- P3: scale Q rows in place: Qs[i] *= atanh(|Q_i|)/|Q_i| ----
  for (int i = w; i < FF; i += 4) Qs[i][l] *= WQ[i];
  __syncthreads();

  // ---- P5: per-slot weighted sum (softmax + log0/mob_scalar collapsed) ----
#pragma unroll 1
  for (int i = w; i < FF; i += 4) {
    const float4* gr = (const float4*)(&Gm[i * FF]);
    v2f ss2 = {0.f, 0.f};
    v2f ac2 = {0.f, 0.f};
#pragma unroll
    for (int jq = 0; jq < FF / 4; ++jq) {
      float4 g4 = gr[jq];
      ss2 += v2f{g4.x, g4.y} + v2f{g4.z, g4.w};
      ac2 = pkfma(v2f{g4.x, g4.y},
                  v2f{Qs[4 * jq + 0][l], Qs[4 * jq + 1][l]}, ac2);
      ac2 = pkfma(v2f{g4.z, g4.w},
                  v2f{Qs[4 * jq + 2][l], Qs[4 * jq + 3][l]}, ac2);
    }
    float acc = (ac2.x + ac2.y) * frcp(ss2.x + ss2.y);
    float dl = Ds[i][l];
    float a2 = wredb(acc * acc);
    float xy0 = wredb(dl * acc);
    float nn = fsq(a2 + 1e-15f);
    float ec = ftanh(nn) * frcp(fmaxf(nn, EPS));
    float fDc = ftanh(q1 * DA[i]) * frcp(DN[i]);
    float x2 = fDc * fDc * D2[i];
    float y2 = ec * ec * a2;
    float xy = fDc * ec * xy0;
    float al = 1.f + 2.f * xy + y2;
    float be = 1.f - x2;
    float rd = frcp(fmaxf(1.f + 2.f * xy + x2 * y2, EPS));
    Ds[i][l] = (al * fDc * dl + be * ec * acc) * rd;
    float h2 = (al * al * x2 + 2.f * al * be * xy + be * be * y2) * rd * rd;
    if (l == 0) D2[i] = h2;  // norm chain deferred to P6
  }
  __syncthreads();

  // ---- P6: aggregates (wave0: e1 over H; wave1: e2 over scaled Q) ----
  if (w < 2) {
    float a1 = 0.f;
    float wh = 1.f;
    if (w == 0) {
      if (l < FF) {
        float h2 = D2[l];
        float nc = clampn(fsq(h2 + 1e-15f));
        wh = fatanh(nc) * frcp(nc);  // log0 weight for H rows
        float dot = dot64(&fs_[0], &Ds[l][0]);
        float d2 = f2 + h2 - 2.f * dot;
        float den = fmaxf((1.f - f2) * (1.f - h2), EPS);
        float arg = fmaxf(1.f + 2.f * d2 * frcp(den), 1.f + 1e-7f);
        a1 = expnacosh(arg);
      }
    } else {
      if (l < FF) {
        float d2 = f2 + Q2[l] - 2.f * Fq[l];
        float den = fmaxf((1.f - f2) * (1.f - Q2[l]), EPS);
        float arg = fmaxf(1.f + 2.f * d2 * frcp(den), 1.f + 1e-7f);
        a1 = expnacosh(arg);
      }
    }
    float s = wredb(a1);
    float c = (l < FF) ? a1 * frcp(s) * wh : 0.f;  // wave1: weight in scaled Q
    float accE = 0.f;
    if (w == 0) {
#pragma unroll
      for (int j = 0; j < FF; ++j) {
        float cj = __int_as_float(__builtin_amdgcn_readlane(__float_as_int(c), j));
        accE = fmaf(cj, Ds[j][l], accE);
      }
    } else {
#pragma unroll
      for (int j = 0; j < FF; ++j) {
        float cj = __int_as_float(__builtin_amdgcn_readlane(__float_as_int(c), j));
        accE = fmaf(cj, Qs[j][l], accE);
      }
    }
    float a2 = wredb(accE * accE);
    float nn = fsq(a2 + 1e-15f);
    float ec = ftanh(nn) * frcp(fmaxf(nn, EPS));
    float nTE = ec * accE;
    float r = (w == 0) ? qsc : qqsc;
    float fsc = ftanh(r * fA) * frcp(fnc);
    float xv = fsc * fv;
    float x2 = fsc * fsc * f2;
    float y2 = ec * ec * a2;
    float xy = wredb(xv * nTE);
    float al = 1.f + 2.f * xy + y2;
    float be = 1.f - x2;
    float rd = frcp(fmaxf(1.f + 2.f * xy + x2 * y2, EPS));
    float ev = (al * xv + be * nTE) * rd;
    float es = (al * al * x2 + 2.f * al * be * xy + be * be * y2) * rd * rd;
    float n1 = clampn(fsq(es + 1e-15f));
    zb[w][l] = fatanh(n1) * frcp(n1) * ev;
  }
  __syncthreads();

  // ---- P7: beta softmax + rst + u (wave0) ----
  if (w == 0) {
    int p_ = l >> 5, c_ = l & 31;
    v2f mm2 = {P.ab1[c_], 0.f};
#pragma unroll
    for (int k = 0; k < DH; k += 2) {
      v2f zv = *(const v2f*)&zb[p_][k];
      v2f av = {P.aw1[k * 32 + c_], P.aw1[(k + 1) * 32 + c_]};
      mm2 = pkfma(zv, av, mm2);
    }
    float tt = ftanh(mm2.x + mm2.y);
    float sr = tt * P.aw2[c_];
    sr = dppadd<0x111>(sr);
    sr = dppadd<0x112>(sr);
    sr = dppadd<0x114>(sr);
    sr = dppadd<0x118>(sr);
    sr = dppadd<0x142>(sr);  // lane31 = sum(0..31), lane63 = sum(32..63)
    float s0 = __int_as_float(__builtin_amdgcn_readlane(__float_as_int(sr), 31));
    float s1 = __int_as_float(__builtin_amdgcn_readlane(__float_as_int(sr), 63));
    float bm = fmaxf(s0, s1);
    float b0 = __expf(s0 - bm), b1 = __expf(s1 - bm);
    float bi = frcp(b0 + b1);
    b0 *= bi;
    b1 *= bi;
    float rv = fmaf(b0, zb[0][l], b1 * zb[1][l]);
    float r2 = wredb(rv * rv);
    float rn = fsq(r2 + 1e-15f);
    float sc = ftanh(rn) * frcp(fmaxf(rn, EPS));
    float rst = sc * rv;
    float rr = sc * sc * r2;
    float rc = clampn(fsq(rr + 1e-15f));
    ub[l] = fatanh(rc) * frcp(rc) * rst;
  }
  __syncthreads();

  // ---- P8: out = exp0(u @ wout + bout), k-split over 4 waves ----
  {
    v2f oo2 = {0.f, 0.f};
#pragma unroll
    for (int k = 0; k < DH / 4; k += 2) {
      int kk = w * (DH / 4) + k;
      v2f uv = *(const v2f*)&ub[kk];
      v2f wv = {P.wout[kk * DH + l], P.wout[(kk + 1) * DH + l]};
      oo2 = pkfma(uv, wv, oo2);
    }
    pb[w][l] = oo2.x + oo2.y;
  }
  __syncthreads();
  if (w == 0) {
    float oo = P.bout[l] + ((pb[0][l] + pb[1][l]) + (pb[2][l] + pb[3][l]));
    float o2 = wredb(oo * oo);
    float on = fsq(o2 + 1e-15f);
    P.out[n * DH + l] = ftanh(on) * frcp(fmaxf(on, EPS)) * oo;
  }
}

extern "C" void kernel_launch(void* const* d_in, const int* in_sizes, int n_in,
                              void* d_out, int out_size, void* d_ws,
                              size_t ws_size, hipStream_t stream) {
  const int* x = (const int*)d_in[0];
  const int* idx_sim = (const int*)d_in[1];
  const int* idx_cor = (const int*)d_in[2];
  const float* p[2][12];
  for (int m = 0; m < 2; ++m)
    for (int k = 0; k < 12; ++k) p[m][k] = (const float*)d_in[3 + m * 12 + k];

  float* fsim = (float*)d_ws;
  float* fcor = fsim + NROW * DH;
  float* out = (float*)d_out;

  FeatParams fps = {p[0][0], p[0][1], p[0][2], p[0][3], fsim};
  FeatParams fpc = {p[1][0], p[1][1], p[1][2], p[1][3], fcor};
  feat_kernel<<<2 * NROW, 64, 0, stream>>>(x, fps, fpc);

  // mode 'sim': D = f[idx_cor], Q = f[idx_sim]; mode 'cor': swapped
  ModeParams m0 = {fsim, idx_cor, idx_sim, p[0][6], p[0][4], p[0][5],
                   p[0][7], p[0][8], p[0][9], p[0][10], p[0][11], out};
  ModeParams m1 = {fcor, idx_sim, idx_cor, p[1][6], p[1][4], p[1][5],
                   p[1][7], p[1][8], p[1][9], p[1][10], p[1][11], out + NROW * DH};
  mode_kernel<<<2 * NROW, 256, 0, stream>>>(m0, m1);
}